// Round 2
// baseline (4621.447 us; speedup 1.0000x reference)
//
#include <hip/hip_runtime.h>

// ContinuousNormalizingFlow: B=32768 rows, D=8, H=64, 100 Euler steps.
// One thread per row; all weights wave-uniform -> SGPR loads; state in VGPRs.

__device__ float g_w1r[64];     // sum_{k<8} W1[j][k]
__device__ float g_w3c[64];     // sum_d W3[d][j]
__device__ float g_w3t[64 * 8]; // W3 transposed: [j][d]

__global__ void cnf_prep(const float* __restrict__ W1, const float* __restrict__ W3) {
    int h = threadIdx.x; // 64 threads
    float s = 0.f;
#pragma unroll
    for (int k = 0; k < 8; ++k) s += W1[h * 9 + k];
    g_w1r[h] = s;
    float c = 0.f;
#pragma unroll
    for (int d = 0; d < 8; ++d) {
        float w = W3[d * 64 + h];
        c += w;
        g_w3t[h * 8 + d] = w;
    }
    g_w3c[h] = c;
}

__device__ __forceinline__ float ftanh(float x) {
    // tanh(x) = 1 - 2/(exp(2x)+1); v_exp_f32 computes 2^x, inf-safe both ends.
    float e = __builtin_amdgcn_exp2f(x * 2.885390081777926815f); // 2*log2(e)
    float r = __builtin_amdgcn_rcpf(e + 1.0f);
    return fmaf(-2.0f, r, 1.0f);
}

__global__ __launch_bounds__(64) void cnf_kernel(
    const float* __restrict__ x0, const float* __restrict__ W1,
    const float* __restrict__ b1, const float* __restrict__ W2,
    const float* __restrict__ b2, const float* __restrict__ W3,
    const float* __restrict__ b3, const int* __restrict__ nsp,
    float* __restrict__ out, int rows) {
    __shared__ float sbuf[64 * 64]; // per-lane private column: sbuf[h*64+lane]
    const int lane = threadIdx.x;
    const int row = blockIdx.x * 64 + lane;
    const int n = *nsp;
    const float dt = 1.0f / (float)n;

    float x[8];
    {
        const float4* p = (const float4*)(x0 + (size_t)row * 8);
        float4 a = p[0], b = p[1];
        x[0] = a.x; x[1] = a.y; x[2] = a.z; x[3] = a.w;
        x[4] = b.x; x[5] = b.y; x[6] = b.z; x[7] = b.w;
    }
    float ld = 0.f;

    for (int i = 0; i < n; ++i) {
        const float t = (float)i * dt;

        // ---------- forward pass at x ----------
        float h1[64];
#pragma unroll
        for (int j = 0; j < 64; ++j) {
            const float* w = W1 + j * 9;
            float a = fmaf(w[8], t, b1[j]);
#pragma unroll
            for (int k = 0; k < 8; ++k) a = fmaf(w[k], x[k], a);
            h1[j] = ftanh(a);
        }

        float dx[8];
#pragma unroll
        for (int d = 0; d < 8; ++d) dx[d] = b3[d];
#pragma unroll 4
        for (int j = 0; j < 64; ++j) {
            const float* w = W2 + j * 64;
            float a0 = 0.f, a1 = 0.f, a2 = 0.f, a3 = 0.f;
#pragma unroll
            for (int h = 0; h < 64; h += 4) {
                a0 = fmaf(w[h + 0], h1[h + 0], a0);
                a1 = fmaf(w[h + 1], h1[h + 1], a1);
                a2 = fmaf(w[h + 2], h1[h + 2], a2);
                a3 = fmaf(w[h + 3], h1[h + 3], a3);
            }
            float h2 = ftanh(((a0 + a1) + (a2 + a3)) + b2[j]);
            const float* w3t = g_w3t + j * 8;
#pragma unroll
            for (int d = 0; d < 8; ++d) dx[d] = fmaf(w3t[d], h2, dx[d]);
        }
#pragma unroll
        for (int d = 0; d < 8; ++d) x[d] = fmaf(dt, dx[d], x[d]);

        // ---------- forward pass at x_new (same t), keep h1' ----------
        float h1p[64];
#pragma unroll
        for (int j = 0; j < 64; ++j) {
            const float* w = W1 + j * 9;
            float a = fmaf(w[8], t, b1[j]);
#pragma unroll
            for (int k = 0; k < 8; ++k) a = fmaf(w[k], x[k], a);
            h1p[j] = ftanh(a);
        }

        // z2' -> dz2 = w3c * (1 - h2'^2), staged to LDS (per-lane column)
#pragma unroll 4
        for (int j = 0; j < 64; ++j) {
            const float* w = W2 + j * 64;
            float a0 = 0.f, a1 = 0.f, a2 = 0.f, a3 = 0.f;
#pragma unroll
            for (int h = 0; h < 64; h += 4) {
                a0 = fmaf(w[h + 0], h1p[h + 0], a0);
                a1 = fmaf(w[h + 1], h1p[h + 1], a1);
                a2 = fmaf(w[h + 2], h1p[h + 2], a2);
                a3 = fmaf(w[h + 3], h1p[h + 3], a3);
            }
            float th = ftanh(((a0 + a1) + (a2 + a3)) + b2[j]);
            sbuf[j * 64 + lane] = g_w3c[j] * fmaf(-th, th, 1.0f);
        }

        // dh1 = dz2 @ W2  (outer h rolled, inner j unrolled, static accs)
        float dh1[64];
#pragma unroll
        for (int j = 0; j < 64; ++j) dh1[j] = 0.f;
#pragma unroll 2
        for (int h = 0; h < 64; ++h) {
            float v = sbuf[h * 64 + lane];
            const float* w = W2 + h * 64;
#pragma unroll
            for (int j = 0; j < 64; ++j) dh1[j] = fmaf(w[j], v, dh1[j]);
        }

        // gsum = sum_j dh1[j]*(1-h1p[j]^2)*w1rowsum[j]
        float g0 = 0.f, g1 = 0.f;
#pragma unroll
        for (int j = 0; j < 64; j += 2) {
            g0 = fmaf(dh1[j + 0] * fmaf(-h1p[j + 0], h1p[j + 0], 1.0f), g_w1r[j + 0], g0);
            g1 = fmaf(dh1[j + 1] * fmaf(-h1p[j + 1], h1p[j + 1], 1.0f), g_w1r[j + 1], g1);
        }
        ld = fmaf(dt, g0 + g1, ld);
    }

    // ---------- epilogue ----------
    float4* po = (float4*)(out + (size_t)row * 8);
    float4 o0, o1;
    o0.x = x[0]; o0.y = x[1]; o0.z = x[2]; o0.w = x[3];
    o1.x = x[4]; o1.y = x[5]; o1.z = x[6]; o1.w = x[7];
    po[0] = o0;
    po[1] = o1;
    out[(size_t)rows * 8 + row] = ld;
}

extern "C" void kernel_launch(void* const* d_in, const int* in_sizes, int n_in,
                              void* d_out, int out_size, void* d_ws, size_t ws_size,
                              hipStream_t stream) {
    const float* x0 = (const float*)d_in[0];
    const float* W1 = (const float*)d_in[1];
    const float* b1 = (const float*)d_in[2];
    const float* W2 = (const float*)d_in[3];
    const float* b2 = (const float*)d_in[4];
    const float* W3 = (const float*)d_in[5];
    const float* b3 = (const float*)d_in[6];
    const int* ns = (const int*)d_in[7];
    float* out = (float*)d_out;
    const int rows = in_sizes[0] / 8; // 32768

    hipLaunchKernelGGL(cnf_prep, dim3(1), dim3(64), 0, stream, W1, W3);
    hipLaunchKernelGGL(cnf_kernel, dim3(rows / 64), dim3(64), 0, stream,
                       x0, W1, b1, W2, b2, W3, b3, ns, out, rows);
}